// Round 4
// baseline (76.502 us; speedup 1.0000x reference)
//
#include <hip/hip_runtime.h>
#include <math.h>

#define NQ   12
#define DIM  4096
#define BLK  256
#define IND  768
#define HD   24
#define NOBS 28
#define STSZ 4352   // 4096 amps + 1-per-32 pad, rounded to 17*256
#define NSLOT 22

typedef float  f32x2 __attribute__((ext_vector_type(2)));
typedef __fp16 f16x2 __attribute__((ext_vector_type(2)));

// ---- fp16 state pack/unpack (compute stays f32) ----
__device__ __forceinline__ unsigned pack2(f32x2 v) {
    f16x2 h = __builtin_amdgcn_cvt_pkrtz(v.x, v.y);
    unsigned u; __builtin_memcpy(&u, &h, 4); return u;
}
__device__ __forceinline__ f32x2 unpack2(unsigned u) {
    f16x2 h; __builtin_memcpy(&h, &u, 4);
    f32x2 v; v.x = (float)h.x; v.y = (float)h.y; return v;
}

// ---- packed complex arithmetic (VOP3P, 2 FMA per instruction) ----
__device__ __forceinline__ f32x2 pk_cmul(f32x2 m, f32x2 u) {
    f32x2 r;
    asm("v_pk_mul_f32 %0, %1, %2 op_sel:[0,0] op_sel_hi:[0,1]"
        : "=v"(r) : "v"(m), "v"(u));
    asm("v_pk_fma_f32 %0, %1, %2, %0 op_sel:[1,1,0] op_sel_hi:[1,0,1] neg_lo:[0,1,0]"
        : "+v"(r) : "v"(m), "v"(u));
    return r;
}
__device__ __forceinline__ void pk_cfma(f32x2& acc, f32x2 m, f32x2 u) {
    asm("v_pk_fma_f32 %0, %1, %2, %0 op_sel:[0,0,0] op_sel_hi:[0,1,1]"
        : "+v"(acc) : "v"(m), "v"(u));
    asm("v_pk_fma_f32 %0, %1, %2, %0 op_sel:[1,1,0] op_sel_hi:[1,0,1] neg_lo:[0,1,0]"
        : "+v"(acc) : "v"(m), "v"(u));
}
__device__ __forceinline__ void pk_fma_plain(f32x2& acc, f32x2 a, f32x2 b) {
    asm("v_pk_fma_f32 %0, %1, %2, %0" : "+v"(acc) : "v"(a), "v"(b));
}

__global__ void __launch_bounds__(BLK, 8) pqm_kernel(
    const float* __restrict__ x,   const float* __restrict__ W1,
    const float* __restrict__ b1,  const float* __restrict__ ln_g,
    const float* __restrict__ ln_b,const float* __restrict__ W2,
    const float* __restrict__ b2,  const float* __restrict__ qw0,
    const float* __restrict__ qw1, const float* __restrict__ qw2,
    const float* __restrict__ scales, const float* __restrict__ biases,
    float* __restrict__ out)
{
    __shared__ unsigned st16[STSZ];     // fp16 statevector, padded slots
    __shared__ float GM[3][NQ][8];      // Rot mats, fused to M=Rot*RY in place
    __shared__ float hbuf[HD];
    __shared__ float angc[NQ], angs[NQ];
    __shared__ float red[16][NSLOT];    // per-16-lane-subgroup partials

    const int t   = threadIdx.x;
    const int row = blockIdx.x;
    float* xs = (float*)st16;           // padded f32 layout: XA(k)=k+4*(k>>5)

    // ---- Phase 1: stage x row (float4, padded) ----
    if (t < 192) {
        const float4 xv = *(const float4*)(x + row * IND + 4 * t);
        int k = 4 * t;
        *(float4*)(xs + (k + 4 * (k >> 5))) = xv;
    }
    __syncthreads();

    // ---- Phase 2: h = x@W1^T + b1 (24 outs, 8 lanes each); Rot mats ----
    {
        int g = t >> 3, l8 = t & 7;
        if (g < HD) {
            const float* wp = W1 + g * IND + l8 * 96;
            float acc = 0.f;
            #pragma unroll
            for (int j = 0; j < 24; ++j) {
                int k = l8 * 96 + 4 * j;
                float4 a4 = *(const float4*)(xs + (k + 4 * (k >> 5)));
                float4 w4 = *(const float4*)(wp + 4 * j);
                acc += a4.x * w4.x + a4.y * w4.y + a4.z * w4.z + a4.w * w4.w;
            }
            acc += __shfl_down(acc, 4, 8);
            acc += __shfl_down(acc, 2, 8);
            acc += __shfl_down(acc, 1, 8);
            if (l8 == 0) hbuf[g] = acc + b1[g];
        } else if (t >= 192 && t < 192 + 36) {
            int li = (t - 192) / NQ, q = (t - 192) % NQ;
            const float* qw = (li == 0) ? qw0 : ((li == 1) ? qw1 : qw2);
            float phi = qw[q*3+0], th = qw[q*3+1], om = qw[q*3+2];
            float c = cosf(0.5f*th), s = sinf(0.5f*th);
            float sp, cp, sm, cm;
            sincosf(0.5f*(phi+om), &sp, &cp);
            sincosf(0.5f*(phi-om), &sm, &cm);
            float* R = GM[li][q];
            R[0] =  cp*c;  R[1] = -sp*c;
            R[2] = -cm*s;  R[3] = -sm*s;
            R[4] =  cm*s;  R[5] = -sm*s;
            R[6] =  cp*c;  R[7] =  sp*c;
        }
    }
    __syncthreads();

    // ---- Phase 3: LN + ReLU + W2 + tanh -> angles; zero fp16 state ----
    if (t < NQ) {
        float mu = 0.f;
        #pragma unroll
        for (int j = 0; j < HD; ++j) mu += hbuf[j];
        mu *= (1.f / HD);
        float var = 0.f;
        #pragma unroll
        for (int j = 0; j < HD; ++j) { float d = hbuf[j] - mu; var += d * d; }
        var *= (1.f / HD);
        float rinv = 1.f / sqrtf(var + 1e-5f);
        float acc = b2[t];
        #pragma unroll
        for (int j = 0; j < HD; ++j) {
            float hn = (hbuf[j] - mu) * rinv * ln_g[j] + ln_b[j];
            acc += fmaxf(hn, 0.f) * W2[t * HD + j];
        }
        float a = tanhf(acc);
        angc[t] = cosf(0.5f * a);
        angs[t] = sinf(0.5f * a);
    }
    #pragma unroll
    for (int i = t; i < STSZ; i += BLK) st16[i] = 0u;
    __syncthreads();

    // ---- Phase 4: fuse M = Rot * RY in place ----
    if (t < 36) {
        int li = t / NQ, q = t % NQ;
        float* R = GM[li][q];
        float r0=R[0],r1=R[1],r2=R[2],r3=R[3],r4=R[4],r5=R[5],r6=R[6],r7=R[7];
        float cr = angc[q], sr = angs[q];
        R[0] =  r0*cr + r2*sr;  R[1] =  r1*cr + r3*sr;
        R[2] = -r0*sr + r2*cr;  R[3] = -r1*sr + r3*cr;
        R[4] =  r4*cr + r6*sr;  R[5] =  r5*cr + r7*sr;
        R[6] = -r4*sr + r6*cr;  R[7] = -r5*sr + r7*cr;
    }
    __syncthreads();

    auto butterflies = [&](f32x2* v, const float (*Mlayer)[8], int qtop) {
        #pragma unroll
        for (int j = 0; j < 4; ++j) {
            const f32x2* Msrc = (const f32x2*)Mlayer[qtop - j];
            f32x2 M0 = Msrc[0], M1 = Msrc[1], M2 = Msrc[2], M3 = Msrc[3];
            #pragma unroll
            for (int r = 0; r < 16; ++r)
                if (!(r & (1 << j))) {
                    f32x2 u = v[r], w = v[r | (1 << j)];
                    f32x2 un = pk_cmul(M0, u); pk_cfma(un, M1, w);
                    f32x2 wn = pk_cmul(M2, u); pk_cfma(wn, M3, w);
                    v[r] = un; v[r | (1 << j)] = wn;
                }
        }
    };

    // Padded address: A(i) = s + (s>>5), s = i ^ ((i>>4)&15)
    f32x2 v[16];
    const int t4    = t & 15;
    const int baseA = 16 * t + (t >> 1);
    const int baseB = 264 * (t >> 4);
    const int tc    = t ^ (t >> 4);
    const int baseC = tc + (tc >> 5);

    for (int l = 0; l < 3; ++l) {
        const float (*M)[8] = GM[l];
        // ---- pass A: idx bits 0-3 in registers (qubits 11-8) ----
        if (l == 0) {
            if (t == 0) {   // |0...0>: only thread 0 has support
                #pragma unroll
                for (int r = 0; r < 16; ++r) { v[r].x = (r == 0) ? 1.f : 0.f; v[r].y = 0.f; }
                butterflies(v, M, 11);
                #pragma unroll
                for (int r = 0; r < 16; ++r) st16[r] = pack2(v[r]);
            }
        } else {
            // gather with folded CNOT ring: i = T ^ R_r (disjoint-bit xors)
            const int T2  = (t << 4) ^ (t << 3);
            const int T2b = T2 ^ ((T2 >> 4) & 15);
            #pragma unroll
            for (int r = 0; r < 16; ++r) {
                const int Rr = r ^ (r >> 1) ^ ((r & 1) ? 0xC00 : 0);
                int s = T2b ^ Rr;
                v[r] = unpack2(st16[s + (s >> 5)]);
            }
            __syncthreads();    // all gathers before any scatter
            butterflies(v, M, 11);
            #pragma unroll
            for (int r = 0; r < 16; ++r) st16[baseA + (r ^ t4)] = pack2(v[r]);
        }
        __syncthreads();
        // ---- pass B: idx bits 4-7 in registers (qubits 7-4) ----
        if (l > 0 || t < 16) {   // layer 0: support only in idx<256
            #pragma unroll
            for (int r = 0; r < 16; ++r)
                v[r] = unpack2(st16[baseB + 16*r + (r>>1) + (t4 ^ r)]);
            butterflies(v, M, 7);
            if (l == 2) {
                // eX4 = <X4 X5> (mask 0xC0: reg bits 2,3) and
                // eX3 = <(U3^dag X U3)_3 X_4> (conjugated through pass-C gate)
                const float* U = GM[2][3];
                float A00  = 2.f*(U[0]*U[4] + U[1]*U[5]);
                float A11  = 2.f*(U[2]*U[6] + U[3]*U[7]);
                float A01r = U[0]*U[6] + U[1]*U[7] + U[4]*U[2] + U[5]*U[3];
                float A01i = U[0]*U[7] - U[1]*U[6] + U[4]*U[3] - U[5]*U[2];
                float S8 = 0.f, SR = 0.f, SI = 0.f, S12 = 0.f;
                #pragma unroll
                for (int r = 0; r < 16; ++r) {
                    f32x2 p8 = v[r ^ 8], pc = v[r ^ 12];
                    S8  += v[r].x*p8.x + v[r].y*p8.y;
                    S12 += v[r].x*pc.x + v[r].y*pc.y;
                    float wx = __shfl_xor(p8.x, 16, 64);
                    float wy = __shfl_xor(p8.y, 16, 64);
                    SR += v[r].x*wx + v[r].y*wy;
                    SI += v[r].x*wy - v[r].y*wx;
                }
                int bb = (t >> 4) & 1;
                float ex3 = (bb ? A11 : A00)*S8 + A01r*SR + (bb ? A01i : -A01i)*SI;
                float ex4 = S12;
                #pragma unroll
                for (int d = 1; d < 16; d <<= 1) {
                    ex3 += __shfl_xor(ex3, d, 64);
                    ex4 += __shfl_xor(ex4, d, 64);
                }
                if ((t & 15) == 0) { red[t >> 4][19] = ex3; red[t >> 4][20] = ex4; }
            }
            #pragma unroll
            for (int r = 0; r < 16; ++r)
                st16[baseB + 16*r + (r>>1) + (t4 ^ r)] = pack2(v[r]);
        }
        __syncthreads();
        // ---- pass C: idx bits 8-11 in registers (qubits 3-0) ----
        #pragma unroll
        for (int r = 0; r < 16; ++r)
            v[r] = unpack2(st16[264 * r + baseC]);
        butterflies(v, M, 3);
        if (l < 2) {
            #pragma unroll
            for (int r = 0; r < 16; ++r)
                st16[264 * r + baseC] = pack2(v[r]);
            __syncthreads();
        }
    }

    // ---- Measurement from pass-C registers (final ring folded into masks) ----
    // v[r] = amp(idx = (r<<8) | t), pre-final-ring state.
    f32x2 a0; a0.x = 0.f; a0.y = 0.f;
    f32x2 a1 = a0, a2 = a0;
    #pragma unroll
    for (int r = 0; r < 16; ++r) {
        pk_fma_plain(a0, v[r], v[r ^ 12]);   // eX0: mask 0xC00
        pk_fma_plain(a1, v[r], v[r ^ 6]);    // eX1: mask 0x600
        pk_fma_plain(a2, v[r], v[r ^ 3]);    // eX2: mask 0x300
    }
    float e0 = a0.x + a0.y, e1 = a1.x + a1.y, e2 = a2.x + a2.y;

    float pr[16];
    #pragma unroll
    for (int r = 0; r < 16; ++r) pr[r] = v[r].x*v[r].x + v[r].y*v[r].y;
    #pragma unroll
    for (int lev = 0; lev < 4; ++lev)
        #pragma unroll
        for (int m = 0; m < 16; ++m)
            if (!(m & (1 << lev))) {
                float A = pr[m], B = pr[m | (1 << lev)];
                pr[m] = A + B; pr[m | (1 << lev)] = A - B;
            }

    const int sub = t & 15, G = t >> 4;
    float sgn = (__popc(sub) & 1) ? -1.f : 1.f;
    float c7 = pr[7] * sgn, cB = pr[11] * sgn;      // eZ0 / eZZ0 (nibble-signed)
    float chF = pr[15], ch0 = pr[0];
    float cC = pr[12], cE = pr[14], c2 = pr[2], c1 = pr[1];

    // 4-level WHT over the 16-lane subgroup for chF (mr=0xF) and ch0 (mr=0)
    #pragma unroll
    for (int lev = 0; lev < 4; ++lev) {
        float oF = __shfl_xor(chF, 1 << lev, 64);
        float o0 = __shfl_xor(ch0, 1 << lev, 64);
        chF = (sub & (1 << lev)) ? (oF - chF) : (chF + oF);
        ch0 = (sub & (1 << lev)) ? (o0 - ch0) : (ch0 + o0);
    }
    // plain 16-lane sums for the single-mask channels
    #pragma unroll
    for (int d = 1; d < 16; d <<= 1) {
        c7 += __shfl_xor(c7, d, 64);  cB += __shfl_xor(cB, d, 64);
        cC += __shfl_xor(cC, d, 64);  cE += __shfl_xor(cE, d, 64);
        c2 += __shfl_xor(c2, d, 64);  c1 += __shfl_xor(c1, d, 64);
        e0 += __shfl_xor(e0, d, 64);  e1 += __shfl_xor(e1, d, 64);
        e2 += __shfl_xor(e2, d, 64);
    }
    if (sub == 0) {
        red[G][0]  = chF; red[G][5]  = ch0;
        red[G][10] = c7;  red[G][11] = cB; red[G][12] = cC; red[G][13] = cE;
        red[G][14] = c2;  red[G][15] = c1;
        red[G][16] = e0;  red[G][17] = e1; red[G][18] = e2;
    } else if (sub == 8)  { red[G][1] = chF; red[G][6] = ch0; }
    else if (sub == 12)   { red[G][2] = chF; }
    else if (sub == 14)   { red[G][3] = chF; }
    else if (sub == 15)   { red[G][4] = chF; }
    else if (sub == 4)    { red[G][7] = ch0; }
    else if (sub == 2)    { red[G][8] = ch0; }
    else if (sub == 1)    { red[G][9] = ch0; }
    __syncthreads();

    if (t < NOBS) {
        // obs -> (partial slot, sign mask over subgroup id G = idx bits 4-7)
        const int oslot[NOBS] = {10,12,13, 0,0,0,0,0, 1,2,3,4,
                                 11,14,15, 5,5,5,5, 6,7,8,9,
                                 16,17,18,19,20};
        const int ogm[NOBS]   = {15, 0, 0, 0,8,12,14,15, 15,15,15,15,
                                 15, 0, 0, 8,4,2,1, 0,0,0,0,
                                 0,0,0,0,0};
        int sl = oslot[t], gm = ogm[t];
        float s = 0.f;
        #pragma unroll
        for (int g = 0; g < 16; ++g) {
            float p = red[g][sl];
            s += (__popc(g & gm) & 1) ? -p : p;
        }
        out[row * NOBS + t] = s * scales[t] + biases[t];
    }
}

extern "C" void kernel_launch(void* const* d_in, const int* in_sizes, int n_in,
                              void* d_out, int out_size, void* d_ws, size_t ws_size,
                              hipStream_t stream) {
    const int Bn = in_sizes[0] / IND;   // 1024
    pqm_kernel<<<dim3(Bn), dim3(BLK), 0, stream>>>(
        (const float*)d_in[0], (const float*)d_in[1], (const float*)d_in[2],
        (const float*)d_in[3], (const float*)d_in[4], (const float*)d_in[5],
        (const float*)d_in[6], (const float*)d_in[7], (const float*)d_in[8],
        (const float*)d_in[9], (const float*)d_in[10], (const float*)d_in[11],
        (float*)d_out);
}

// Round 5
// 62.823 us; speedup vs baseline: 1.2177x; 1.2177x over previous
//
#include <hip/hip_runtime.h>
#include <math.h>

#define NQ   12
#define DIM  4096
#define BLK  256
#define IND  768
#define HD   24
#define NOBS 28
#define STSZ 4352   // 4096 amps + 1-per-32 pad, rounded to 17*256
#define NSLOT 22

typedef float  f32x2 __attribute__((ext_vector_type(2)));
typedef __fp16 f16x2 __attribute__((ext_vector_type(2)));

// ---- fp16 state pack/unpack (compute stays f32) ----
__device__ __forceinline__ unsigned pack2(f32x2 v) {
    f16x2 h = __builtin_amdgcn_cvt_pkrtz(v.x, v.y);
    unsigned u; __builtin_memcpy(&u, &h, 4); return u;
}
__device__ __forceinline__ f32x2 unpack2(unsigned u) {
    f16x2 h; __builtin_memcpy(&h, &u, 4);
    f32x2 v; v.x = (float)h.x; v.y = (float)h.y; return v;
}

// ---- packed complex arithmetic (VOP3P, 2 FMA per instruction) ----
__device__ __forceinline__ f32x2 pk_cmul(f32x2 m, f32x2 u) {
    f32x2 r;
    asm("v_pk_mul_f32 %0, %1, %2 op_sel:[0,0] op_sel_hi:[0,1]"
        : "=v"(r) : "v"(m), "v"(u));
    asm("v_pk_fma_f32 %0, %1, %2, %0 op_sel:[1,1,0] op_sel_hi:[1,0,1] neg_lo:[0,1,0]"
        : "+v"(r) : "v"(m), "v"(u));
    return r;
}
__device__ __forceinline__ void pk_cfma(f32x2& acc, f32x2 m, f32x2 u) {
    asm("v_pk_fma_f32 %0, %1, %2, %0 op_sel:[0,0,0] op_sel_hi:[0,1,1]"
        : "+v"(acc) : "v"(m), "v"(u));
    asm("v_pk_fma_f32 %0, %1, %2, %0 op_sel:[1,1,0] op_sel_hi:[1,0,1] neg_lo:[0,1,0]"
        : "+v"(acc) : "v"(m), "v"(u));
}
__device__ __forceinline__ void pk_fma_plain(f32x2& acc, f32x2 a, f32x2 b) {
    asm("v_pk_fma_f32 %0, %1, %2, %0" : "+v"(acc) : "v"(a), "v"(b));
}

__global__ void __launch_bounds__(BLK, 6) pqm_kernel(
    const float* __restrict__ x,   const float* __restrict__ W1,
    const float* __restrict__ b1,  const float* __restrict__ ln_g,
    const float* __restrict__ ln_b,const float* __restrict__ W2,
    const float* __restrict__ b2,  const float* __restrict__ qw0,
    const float* __restrict__ qw1, const float* __restrict__ qw2,
    const float* __restrict__ scales, const float* __restrict__ biases,
    float* __restrict__ out)
{
    __shared__ unsigned st16[STSZ];     // fp16 statevector, padded slots
    __shared__ float GM[3][NQ][8];      // Rot mats, fused to M=Rot*RY in place
    __shared__ float hbuf[HD];
    __shared__ float angc[NQ], angs[NQ];
    __shared__ float red[16][NSLOT];    // per-16-lane-subgroup partials

    const int t   = threadIdx.x;
    const int row = blockIdx.x;
    float* xs = (float*)st16;           // padded f32 layout: XA(k)=k+4*(k>>5)

    // ---- Phase 1: stage x row (float4, padded) ----
    if (t < 192) {
        const float4 xv = *(const float4*)(x + row * IND + 4 * t);
        int k = 4 * t;
        *(float4*)(xs + (k + 4 * (k >> 5))) = xv;
    }
    __syncthreads();

    // ---- Phase 2: h = x@W1^T + b1 (24 outs, 8 lanes each); Rot mats ----
    {
        int g = t >> 3, l8 = t & 7;
        if (g < HD) {
            const float* wp = W1 + g * IND + l8 * 96;
            float acc = 0.f;
            #pragma unroll
            for (int j = 0; j < 24; ++j) {
                int k = l8 * 96 + 4 * j;
                float4 a4 = *(const float4*)(xs + (k + 4 * (k >> 5)));
                float4 w4 = *(const float4*)(wp + 4 * j);
                acc += a4.x * w4.x + a4.y * w4.y + a4.z * w4.z + a4.w * w4.w;
            }
            acc += __shfl_down(acc, 4, 8);
            acc += __shfl_down(acc, 2, 8);
            acc += __shfl_down(acc, 1, 8);
            if (l8 == 0) hbuf[g] = acc + b1[g];
        } else if (t >= 192 && t < 192 + 36) {
            int li = (t - 192) / NQ, q = (t - 192) % NQ;
            const float* qw = (li == 0) ? qw0 : ((li == 1) ? qw1 : qw2);
            float phi = qw[q*3+0], th = qw[q*3+1], om = qw[q*3+2];
            float c = cosf(0.5f*th), s = sinf(0.5f*th);
            float sp, cp, sm, cm;
            sincosf(0.5f*(phi+om), &sp, &cp);
            sincosf(0.5f*(phi-om), &sm, &cm);
            float* R = GM[li][q];
            R[0] =  cp*c;  R[1] = -sp*c;
            R[2] = -cm*s;  R[3] = -sm*s;
            R[4] =  cm*s;  R[5] = -sm*s;
            R[6] =  cp*c;  R[7] =  sp*c;
        }
    }
    __syncthreads();

    // ---- Phase 3: LN + ReLU + W2 + tanh -> angles; zero fp16 state ----
    if (t < NQ) {
        float mu = 0.f;
        #pragma unroll
        for (int j = 0; j < HD; ++j) mu += hbuf[j];
        mu *= (1.f / HD);
        float var = 0.f;
        #pragma unroll
        for (int j = 0; j < HD; ++j) { float d = hbuf[j] - mu; var += d * d; }
        var *= (1.f / HD);
        float rinv = 1.f / sqrtf(var + 1e-5f);
        float acc = b2[t];
        #pragma unroll
        for (int j = 0; j < HD; ++j) {
            float hn = (hbuf[j] - mu) * rinv * ln_g[j] + ln_b[j];
            acc += fmaxf(hn, 0.f) * W2[t * HD + j];
        }
        float a = tanhf(acc);
        angc[t] = cosf(0.5f * a);
        angs[t] = sinf(0.5f * a);
    }
    #pragma unroll
    for (int i = t; i < STSZ; i += BLK) st16[i] = 0u;
    __syncthreads();

    // ---- Phase 4: fuse M = Rot * RY in place ----
    if (t < 36) {
        int li = t / NQ, q = t % NQ;
        float* R = GM[li][q];
        float r0=R[0],r1=R[1],r2=R[2],r3=R[3],r4=R[4],r5=R[5],r6=R[6],r7=R[7];
        float cr = angc[q], sr = angs[q];
        R[0] =  r0*cr + r2*sr;  R[1] =  r1*cr + r3*sr;
        R[2] = -r0*sr + r2*cr;  R[3] = -r1*sr + r3*cr;
        R[4] =  r4*cr + r6*sr;  R[5] =  r5*cr + r7*sr;
        R[6] = -r4*sr + r6*cr;  R[7] = -r5*sr + r7*cr;
    }
    __syncthreads();

    auto butterflies = [&](f32x2* v, const float (*Mlayer)[8], int qtop) {
        #pragma unroll
        for (int j = 0; j < 4; ++j) {
            const f32x2* Msrc = (const f32x2*)Mlayer[qtop - j];
            f32x2 M0 = Msrc[0], M1 = Msrc[1], M2 = Msrc[2], M3 = Msrc[3];
            #pragma unroll
            for (int r = 0; r < 16; ++r)
                if (!(r & (1 << j))) {
                    f32x2 u = v[r], w = v[r | (1 << j)];
                    f32x2 un = pk_cmul(M0, u); pk_cfma(un, M1, w);
                    f32x2 wn = pk_cmul(M2, u); pk_cfma(wn, M3, w);
                    v[r] = un; v[r | (1 << j)] = wn;
                }
        }
    };

    // Padded address: A(i) = s + (s>>5), s = i ^ ((i>>4)&15)
    f32x2 v[16];
    const int t4    = t & 15;
    const int baseA = 16 * t + (t >> 1);
    const int baseB = 264 * (t >> 4);
    const int tc    = t ^ (t >> 4);
    const int baseC = tc + (tc >> 5);

    for (int l = 0; l < 3; ++l) {
        const float (*M)[8] = GM[l];
        // ---- pass A: idx bits 0-3 in registers (qubits 11-8) ----
        if (l == 0) {
            if (t == 0) {   // |0...0>: only thread 0 has support
                #pragma unroll
                for (int r = 0; r < 16; ++r) { v[r].x = (r == 0) ? 1.f : 0.f; v[r].y = 0.f; }
                butterflies(v, M, 11);
                #pragma unroll
                for (int r = 0; r < 16; ++r) st16[r] = pack2(v[r]);
            }
        } else {
            // gather with folded CNOT ring: i = T ^ R_r (disjoint-bit xors)
            const int T2  = (t << 4) ^ (t << 3);
            const int T2b = T2 ^ ((T2 >> 4) & 15);
            #pragma unroll
            for (int r = 0; r < 16; ++r) {
                const int Rr = r ^ (r >> 1) ^ ((r & 1) ? 0xC00 : 0);
                int s = T2b ^ Rr;
                v[r] = unpack2(st16[s + (s >> 5)]);
            }
            __syncthreads();    // all gathers before any scatter
            butterflies(v, M, 11);
            #pragma unroll
            for (int r = 0; r < 16; ++r) st16[baseA + (r ^ t4)] = pack2(v[r]);
        }
        __syncthreads();
        // ---- pass B: idx bits 4-7 in registers (qubits 7-4) ----
        if (l > 0 || t < 16) {   // layer 0: support only in idx<256
            #pragma unroll
            for (int r = 0; r < 16; ++r)
                v[r] = unpack2(st16[baseB + 16*r + (r>>1) + (t4 ^ r)]);
            butterflies(v, M, 7);
            if (l == 2) {
                // eX4 = <X4 X5> (mask 0xC0: reg bits 2,3) and
                // eX3 = <(U3^dag X U3)_3 X_4> (conjugated through pass-C gate)
                const float* U = GM[2][3];
                float A00  = 2.f*(U[0]*U[4] + U[1]*U[5]);
                float A11  = 2.f*(U[2]*U[6] + U[3]*U[7]);
                float A01r = U[0]*U[6] + U[1]*U[7] + U[4]*U[2] + U[5]*U[3];
                float A01i = U[0]*U[7] - U[1]*U[6] + U[4]*U[3] - U[5]*U[2];
                float S8 = 0.f, SR = 0.f, SI = 0.f, S12 = 0.f;
                #pragma unroll
                for (int r = 0; r < 16; ++r) {
                    f32x2 p8 = v[r ^ 8], pc = v[r ^ 12];
                    S8  += v[r].x*p8.x + v[r].y*p8.y;
                    S12 += v[r].x*pc.x + v[r].y*pc.y;
                    float wx = __shfl_xor(p8.x, 16, 64);
                    float wy = __shfl_xor(p8.y, 16, 64);
                    SR += v[r].x*wx + v[r].y*wy;
                    SI += v[r].x*wy - v[r].y*wx;
                }
                int bb = (t >> 4) & 1;
                float ex3 = (bb ? A11 : A00)*S8 + A01r*SR + (bb ? A01i : -A01i)*SI;
                float ex4 = S12;
                #pragma unroll
                for (int d = 1; d < 16; d <<= 1) {
                    ex3 += __shfl_xor(ex3, d, 64);
                    ex4 += __shfl_xor(ex4, d, 64);
                }
                if ((t & 15) == 0) { red[t >> 4][19] = ex3; red[t >> 4][20] = ex4; }
            }
            #pragma unroll
            for (int r = 0; r < 16; ++r)
                st16[baseB + 16*r + (r>>1) + (t4 ^ r)] = pack2(v[r]);
        }
        __syncthreads();
        // ---- pass C: idx bits 8-11 in registers (qubits 3-0) ----
        #pragma unroll
        for (int r = 0; r < 16; ++r)
            v[r] = unpack2(st16[264 * r + baseC]);
        butterflies(v, M, 3);
        if (l < 2) {
            #pragma unroll
            for (int r = 0; r < 16; ++r)
                st16[264 * r + baseC] = pack2(v[r]);
            __syncthreads();
        }
    }

    // ---- Measurement from pass-C registers (final ring folded into masks) ----
    // v[r] = amp(idx = (r<<8) | t), pre-final-ring state.
    f32x2 a0; a0.x = 0.f; a0.y = 0.f;
    f32x2 a1 = a0, a2 = a0;
    #pragma unroll
    for (int r = 0; r < 16; ++r) {
        pk_fma_plain(a0, v[r], v[r ^ 12]);   // eX0: mask 0xC00
        pk_fma_plain(a1, v[r], v[r ^ 6]);    // eX1: mask 0x600
        pk_fma_plain(a2, v[r], v[r ^ 3]);    // eX2: mask 0x300
    }
    float e0 = a0.x + a0.y, e1 = a1.x + a1.y, e2 = a2.x + a2.y;

    float pr[16];
    #pragma unroll
    for (int r = 0; r < 16; ++r) pr[r] = v[r].x*v[r].x + v[r].y*v[r].y;
    #pragma unroll
    for (int lev = 0; lev < 4; ++lev)
        #pragma unroll
        for (int m = 0; m < 16; ++m)
            if (!(m & (1 << lev))) {
                float A = pr[m], B = pr[m | (1 << lev)];
                pr[m] = A + B; pr[m | (1 << lev)] = A - B;
            }

    const int sub = t & 15, G = t >> 4;
    float sgn = (__popc(sub) & 1) ? -1.f : 1.f;
    float c7 = pr[7] * sgn, cB = pr[11] * sgn;      // eZ0 / eZZ0 (nibble-signed)
    float chF = pr[15], ch0 = pr[0];
    float cC = pr[12], cE = pr[14], c2 = pr[2], c1 = pr[1];

    // 4-level WHT over the 16-lane subgroup for chF (mr=0xF) and ch0 (mr=0)
    #pragma unroll
    for (int lev = 0; lev < 4; ++lev) {
        float oF = __shfl_xor(chF, 1 << lev, 64);
        float o0 = __shfl_xor(ch0, 1 << lev, 64);
        chF = (sub & (1 << lev)) ? (oF - chF) : (chF + oF);
        ch0 = (sub & (1 << lev)) ? (o0 - ch0) : (ch0 + o0);
    }
    // plain 16-lane sums for the single-mask channels
    #pragma unroll
    for (int d = 1; d < 16; d <<= 1) {
        c7 += __shfl_xor(c7, d, 64);  cB += __shfl_xor(cB, d, 64);
        cC += __shfl_xor(cC, d, 64);  cE += __shfl_xor(cE, d, 64);
        c2 += __shfl_xor(c2, d, 64);  c1 += __shfl_xor(c1, d, 64);
        e0 += __shfl_xor(e0, d, 64);  e1 += __shfl_xor(e1, d, 64);
        e2 += __shfl_xor(e2, d, 64);
    }
    if (sub == 0) {
        red[G][0]  = chF; red[G][5]  = ch0;
        red[G][10] = c7;  red[G][11] = cB; red[G][12] = cC; red[G][13] = cE;
        red[G][14] = c2;  red[G][15] = c1;
        red[G][16] = e0;  red[G][17] = e1; red[G][18] = e2;
    } else if (sub == 8)  { red[G][1] = chF; red[G][6] = ch0; }
    else if (sub == 12)   { red[G][2] = chF; }
    else if (sub == 14)   { red[G][3] = chF; }
    else if (sub == 15)   { red[G][4] = chF; }
    else if (sub == 4)    { red[G][7] = ch0; }
    else if (sub == 2)    { red[G][8] = ch0; }
    else if (sub == 1)    { red[G][9] = ch0; }
    __syncthreads();

    if (t < NOBS) {
        // obs -> (partial slot, sign mask over subgroup id G = idx bits 4-7)
        const int oslot[NOBS] = {10,12,13, 0,0,0,0,0, 1,2,3,4,
                                 11,14,15, 5,5,5,5, 6,7,8,9,
                                 16,17,18,19,20};
        const int ogm[NOBS]   = {15, 0, 0, 0,8,12,14,15, 15,15,15,15,
                                 15, 0, 0, 8,4,2,1, 0,0,0,0,
                                 0,0,0,0,0};
        int sl = oslot[t], gm = ogm[t];
        float s = 0.f;
        #pragma unroll
        for (int g = 0; g < 16; ++g) {
            float p = red[g][sl];
            s += (__popc(g & gm) & 1) ? -p : p;
        }
        out[row * NOBS + t] = s * scales[t] + biases[t];
    }
}

extern "C" void kernel_launch(void* const* d_in, const int* in_sizes, int n_in,
                              void* d_out, int out_size, void* d_ws, size_t ws_size,
                              hipStream_t stream) {
    const int Bn = in_sizes[0] / IND;   // 1024
    pqm_kernel<<<dim3(Bn), dim3(BLK), 0, stream>>>(
        (const float*)d_in[0], (const float*)d_in[1], (const float*)d_in[2],
        (const float*)d_in[3], (const float*)d_in[4], (const float*)d_in[5],
        (const float*)d_in[6], (const float*)d_in[7], (const float*)d_in[8],
        (const float*)d_in[9], (const float*)d_in[10], (const float*)d_in[11],
        (float*)d_out);
}

// Round 6
// 44.216 us; speedup vs baseline: 1.7302x; 1.4208x over previous
//
#include <hip/hip_runtime.h>
#include <math.h>

#define NQ   12
#define DIM  4096
#define BLK  256
#define IND  768
#define HD   24
#define NOBS 28
#define STSZ 4352   // 4096 amps + 1-per-32 pad, rounded to 17*256
#define NSLOT 22

typedef float  f32x2 __attribute__((ext_vector_type(2)));
typedef __fp16 f16x2 __attribute__((ext_vector_type(2)));

// ---- fp16 state pack/unpack (compute stays f32) ----
__device__ __forceinline__ unsigned pack2(f32x2 v) {
    f16x2 h = __builtin_amdgcn_cvt_pkrtz(v.x, v.y);
    unsigned u; __builtin_memcpy(&u, &h, 4); return u;
}
__device__ __forceinline__ f32x2 unpack2(unsigned u) {
    f16x2 h; __builtin_memcpy(&h, &u, 4);
    f32x2 v; v.x = (float)h.x; v.y = (float)h.y; return v;
}

// ---- packed complex arithmetic (VOP3P, 2 FMA per instruction) ----
__device__ __forceinline__ f32x2 pk_cmul(f32x2 m, f32x2 u) {
    f32x2 r;
    asm("v_pk_mul_f32 %0, %1, %2 op_sel:[0,0] op_sel_hi:[0,1]"
        : "=v"(r) : "v"(m), "v"(u));
    asm("v_pk_fma_f32 %0, %1, %2, %0 op_sel:[1,1,0] op_sel_hi:[1,0,1] neg_lo:[0,1,0]"
        : "+v"(r) : "v"(m), "v"(u));
    return r;
}
__device__ __forceinline__ void pk_cfma(f32x2& acc, f32x2 m, f32x2 u) {
    asm("v_pk_fma_f32 %0, %1, %2, %0 op_sel:[0,0,0] op_sel_hi:[0,1,1]"
        : "+v"(acc) : "v"(m), "v"(u));
    asm("v_pk_fma_f32 %0, %1, %2, %0 op_sel:[1,1,0] op_sel_hi:[1,0,1] neg_lo:[0,1,0]"
        : "+v"(acc) : "v"(m), "v"(u));
}
__device__ __forceinline__ void pk_fma_plain(f32x2& acc, f32x2 a, f32x2 b) {
    asm("v_pk_fma_f32 %0, %1, %2, %0" : "+v"(acc) : "v"(a), "v"(b));
}

__global__ void __launch_bounds__(BLK) pqm_kernel(
    const float* __restrict__ x,   const float* __restrict__ W1,
    const float* __restrict__ b1,  const float* __restrict__ ln_g,
    const float* __restrict__ ln_b,const float* __restrict__ W2,
    const float* __restrict__ b2,  const float* __restrict__ qw0,
    const float* __restrict__ qw1, const float* __restrict__ qw2,
    const float* __restrict__ scales, const float* __restrict__ biases,
    float* __restrict__ out)
{
    __shared__ unsigned st16[STSZ];     // fp16 statevector, padded slots
    __shared__ float GM[3][NQ][8];      // Rot mats, fused to M=Rot*RY in place
    __shared__ float hbuf[HD];
    __shared__ float angc[NQ], angs[NQ];
    __shared__ float red[16][NSLOT];    // per-16-lane-subgroup partials

    const int t   = threadIdx.x;
    const int row = blockIdx.x;
    float* xs = (float*)st16;           // padded f32 layout: XA(k)=k+4*(k>>5)

    // ---- Phase 1: stage x row (float4, padded) ----
    if (t < 192) {
        const float4 xv = *(const float4*)(x + row * IND + 4 * t);
        int k = 4 * t;
        *(float4*)(xs + (k + 4 * (k >> 5))) = xv;
    }
    __syncthreads();

    // ---- Phase 2: h = x@W1^T + b1 (24 outs, 8 lanes each); Rot mats ----
    {
        int g = t >> 3, l8 = t & 7;
        if (g < HD) {
            const float* wp = W1 + g * IND + l8 * 96;
            float acc = 0.f;
            #pragma unroll
            for (int j = 0; j < 24; ++j) {
                int k = l8 * 96 + 4 * j;
                float4 a4 = *(const float4*)(xs + (k + 4 * (k >> 5)));
                float4 w4 = *(const float4*)(wp + 4 * j);
                acc += a4.x * w4.x + a4.y * w4.y + a4.z * w4.z + a4.w * w4.w;
            }
            acc += __shfl_down(acc, 4, 8);
            acc += __shfl_down(acc, 2, 8);
            acc += __shfl_down(acc, 1, 8);
            if (l8 == 0) hbuf[g] = acc + b1[g];
        } else if (t >= 192 && t < 192 + 36) {
            int li = (t - 192) / NQ, q = (t - 192) % NQ;
            const float* qw = (li == 0) ? qw0 : ((li == 1) ? qw1 : qw2);
            float phi = qw[q*3+0], th = qw[q*3+1], om = qw[q*3+2];
            float c = cosf(0.5f*th), s = sinf(0.5f*th);
            float sp, cp, sm, cm;
            sincosf(0.5f*(phi+om), &sp, &cp);
            sincosf(0.5f*(phi-om), &sm, &cm);
            float* R = GM[li][q];
            R[0] =  cp*c;  R[1] = -sp*c;
            R[2] = -cm*s;  R[3] = -sm*s;
            R[4] =  cm*s;  R[5] = -sm*s;
            R[6] =  cp*c;  R[7] =  sp*c;
        }
    }
    __syncthreads();

    // ---- Phase 3: LN + ReLU + W2 + tanh -> angles; zero fp16 state ----
    if (t < NQ) {
        float mu = 0.f;
        #pragma unroll
        for (int j = 0; j < HD; ++j) mu += hbuf[j];
        mu *= (1.f / HD);
        float var = 0.f;
        #pragma unroll
        for (int j = 0; j < HD; ++j) { float d = hbuf[j] - mu; var += d * d; }
        var *= (1.f / HD);
        float rinv = 1.f / sqrtf(var + 1e-5f);
        float acc = b2[t];
        #pragma unroll
        for (int j = 0; j < HD; ++j) {
            float hn = (hbuf[j] - mu) * rinv * ln_g[j] + ln_b[j];
            acc += fmaxf(hn, 0.f) * W2[t * HD + j];
        }
        float a = tanhf(acc);
        angc[t] = cosf(0.5f * a);
        angs[t] = sinf(0.5f * a);
    }
    #pragma unroll
    for (int i = t; i < STSZ; i += BLK) st16[i] = 0u;
    __syncthreads();

    // ---- Phase 4: fuse M = Rot * RY in place ----
    if (t < 36) {
        int li = t / NQ, q = t % NQ;
        float* R = GM[li][q];
        float r0=R[0],r1=R[1],r2=R[2],r3=R[3],r4=R[4],r5=R[5],r6=R[6],r7=R[7];
        float cr = angc[q], sr = angs[q];
        R[0] =  r0*cr + r2*sr;  R[1] =  r1*cr + r3*sr;
        R[2] = -r0*sr + r2*cr;  R[3] = -r1*sr + r3*cr;
        R[4] =  r4*cr + r6*sr;  R[5] =  r5*cr + r7*sr;
        R[6] = -r4*sr + r6*cr;  R[7] = -r5*sr + r7*cr;
    }
    __syncthreads();

    auto butterflies = [&](f32x2* v, const float (*Mlayer)[8], int qtop) {
        #pragma unroll
        for (int j = 0; j < 4; ++j) {
            const f32x2* Msrc = (const f32x2*)Mlayer[qtop - j];
            f32x2 M0 = Msrc[0], M1 = Msrc[1], M2 = Msrc[2], M3 = Msrc[3];
            #pragma unroll
            for (int r = 0; r < 16; ++r)
                if (!(r & (1 << j))) {
                    f32x2 u = v[r], w = v[r | (1 << j)];
                    f32x2 un = pk_cmul(M0, u); pk_cfma(un, M1, w);
                    f32x2 wn = pk_cmul(M2, u); pk_cfma(wn, M3, w);
                    v[r] = un; v[r | (1 << j)] = wn;
                }
        }
    };

    // Padded address: A(i) = s + (s>>5), s = i ^ ((i>>4)&15)
    f32x2 v[16];
    const int t4    = t & 15;
    const int baseA = 16 * t + (t >> 1);
    const int baseB = 264 * (t >> 4);
    const int tc    = t ^ (t >> 4);
    const int baseC = tc + (tc >> 5);

    for (int l = 0; l < 3; ++l) {
        const float (*M)[8] = GM[l];
        // ---- pass A: idx bits 0-3 in registers (qubits 11-8) ----
        if (l == 0) {
            if (t == 0) {   // |0...0>: only thread 0 has support
                #pragma unroll
                for (int r = 0; r < 16; ++r) { v[r].x = (r == 0) ? 1.f : 0.f; v[r].y = 0.f; }
                butterflies(v, M, 11);
                #pragma unroll
                for (int r = 0; r < 16; ++r) st16[r] = pack2(v[r]);
            }
        } else {
            // gather with folded CNOT ring: i = T ^ R_r (disjoint-bit xors)
            const int T2  = (t << 4) ^ (t << 3);
            const int T2b = T2 ^ ((T2 >> 4) & 15);
            #pragma unroll
            for (int r = 0; r < 16; ++r) {
                const int Rr = r ^ (r >> 1) ^ ((r & 1) ? 0xC00 : 0);
                int s = T2b ^ Rr;
                v[r] = unpack2(st16[s + (s >> 5)]);
            }
            __syncthreads();    // all gathers before any scatter
            butterflies(v, M, 11);
            #pragma unroll
            for (int r = 0; r < 16; ++r) st16[baseA + (r ^ t4)] = pack2(v[r]);
        }
        __syncthreads();
        // ---- pass B: idx bits 4-7 in registers (qubits 7-4) ----
        if (l > 0 || t < 16) {   // layer 0: support only in idx<256
            #pragma unroll
            for (int r = 0; r < 16; ++r)
                v[r] = unpack2(st16[baseB + 16*r + (r>>1) + (t4 ^ r)]);
            butterflies(v, M, 7);
            if (l == 2) {
                // eX4 = <X4 X5> (mask 0xC0: reg bits 2,3) and
                // eX3 = <(U3^dag X U3)_3 X_4> (conjugated through pass-C gate)
                const float* U = GM[2][3];
                float A00  = 2.f*(U[0]*U[4] + U[1]*U[5]);
                float A11  = 2.f*(U[2]*U[6] + U[3]*U[7]);
                float A01r = U[0]*U[6] + U[1]*U[7] + U[4]*U[2] + U[5]*U[3];
                float A01i = U[0]*U[7] - U[1]*U[6] + U[4]*U[3] - U[5]*U[2];
                float S8 = 0.f, SR = 0.f, SI = 0.f, S12 = 0.f;
                #pragma unroll
                for (int r = 0; r < 16; ++r) {
                    f32x2 p8 = v[r ^ 8], pc = v[r ^ 12];
                    S8  += v[r].x*p8.x + v[r].y*p8.y;
                    S12 += v[r].x*pc.x + v[r].y*pc.y;
                    float wx = __shfl_xor(p8.x, 16, 64);
                    float wy = __shfl_xor(p8.y, 16, 64);
                    SR += v[r].x*wx + v[r].y*wy;
                    SI += v[r].x*wy - v[r].y*wx;
                }
                int bb = (t >> 4) & 1;
                float ex3 = (bb ? A11 : A00)*S8 + A01r*SR + (bb ? A01i : -A01i)*SI;
                float ex4 = S12;
                #pragma unroll
                for (int d = 1; d < 16; d <<= 1) {
                    ex3 += __shfl_xor(ex3, d, 64);
                    ex4 += __shfl_xor(ex4, d, 64);
                }
                if ((t & 15) == 0) { red[t >> 4][19] = ex3; red[t >> 4][20] = ex4; }
            }
            #pragma unroll
            for (int r = 0; r < 16; ++r)
                st16[baseB + 16*r + (r>>1) + (t4 ^ r)] = pack2(v[r]);
        }
        __syncthreads();
        // ---- pass C: idx bits 8-11 in registers (qubits 3-0) ----
        #pragma unroll
        for (int r = 0; r < 16; ++r)
            v[r] = unpack2(st16[264 * r + baseC]);
        butterflies(v, M, 3);
        if (l < 2) {
            #pragma unroll
            for (int r = 0; r < 16; ++r)
                st16[264 * r + baseC] = pack2(v[r]);
            __syncthreads();
        }
    }

    // ---- Measurement from pass-C registers (final ring folded into masks) ----
    // v[r] = amp(idx = (r<<8) | t), pre-final-ring state.
    f32x2 a0; a0.x = 0.f; a0.y = 0.f;
    f32x2 a1 = a0, a2 = a0;
    #pragma unroll
    for (int r = 0; r < 16; ++r) {
        pk_fma_plain(a0, v[r], v[r ^ 12]);   // eX0: mask 0xC00
        pk_fma_plain(a1, v[r], v[r ^ 6]);    // eX1: mask 0x600
        pk_fma_plain(a2, v[r], v[r ^ 3]);    // eX2: mask 0x300
    }
    float e0 = a0.x + a0.y, e1 = a1.x + a1.y, e2 = a2.x + a2.y;

    float pr[16];
    #pragma unroll
    for (int r = 0; r < 16; ++r) pr[r] = v[r].x*v[r].x + v[r].y*v[r].y;
    #pragma unroll
    for (int lev = 0; lev < 4; ++lev)
        #pragma unroll
        for (int m = 0; m < 16; ++m)
            if (!(m & (1 << lev))) {
                float A = pr[m], B = pr[m | (1 << lev)];
                pr[m] = A + B; pr[m | (1 << lev)] = A - B;
            }

    const int sub = t & 15, G = t >> 4;
    float sgn = (__popc(sub) & 1) ? -1.f : 1.f;
    float c7 = pr[7] * sgn, cB = pr[11] * sgn;      // eZ0 / eZZ0 (nibble-signed)
    float chF = pr[15], ch0 = pr[0];
    float cC = pr[12], cE = pr[14], c2 = pr[2], c1 = pr[1];

    // 4-level WHT over the 16-lane subgroup for chF (mr=0xF) and ch0 (mr=0)
    #pragma unroll
    for (int lev = 0; lev < 4; ++lev) {
        float oF = __shfl_xor(chF, 1 << lev, 64);
        float o0 = __shfl_xor(ch0, 1 << lev, 64);
        chF = (sub & (1 << lev)) ? (oF - chF) : (chF + oF);
        ch0 = (sub & (1 << lev)) ? (o0 - ch0) : (ch0 + o0);
    }
    // plain 16-lane sums for the single-mask channels
    #pragma unroll
    for (int d = 1; d < 16; d <<= 1) {
        c7 += __shfl_xor(c7, d, 64);  cB += __shfl_xor(cB, d, 64);
        cC += __shfl_xor(cC, d, 64);  cE += __shfl_xor(cE, d, 64);
        c2 += __shfl_xor(c2, d, 64);  c1 += __shfl_xor(c1, d, 64);
        e0 += __shfl_xor(e0, d, 64);  e1 += __shfl_xor(e1, d, 64);
        e2 += __shfl_xor(e2, d, 64);
    }
    if (sub == 0) {
        red[G][0]  = chF; red[G][5]  = ch0;
        red[G][10] = c7;  red[G][11] = cB; red[G][12] = cC; red[G][13] = cE;
        red[G][14] = c2;  red[G][15] = c1;
        red[G][16] = e0;  red[G][17] = e1; red[G][18] = e2;
    } else if (sub == 8)  { red[G][1] = chF; red[G][6] = ch0; }
    else if (sub == 12)   { red[G][2] = chF; }
    else if (sub == 14)   { red[G][3] = chF; }
    else if (sub == 15)   { red[G][4] = chF; }
    else if (sub == 4)    { red[G][7] = ch0; }
    else if (sub == 2)    { red[G][8] = ch0; }
    else if (sub == 1)    { red[G][9] = ch0; }
    __syncthreads();

    if (t < NOBS) {
        // obs -> (partial slot, sign mask over subgroup id G = idx bits 4-7)
        const int oslot[NOBS] = {10,12,13, 0,0,0,0,0, 1,2,3,4,
                                 11,14,15, 5,5,5,5, 6,7,8,9,
                                 16,17,18,19,20};
        const int ogm[NOBS]   = {15, 0, 0, 0,8,12,14,15, 15,15,15,15,
                                 15, 0, 0, 8,4,2,1, 0,0,0,0,
                                 0,0,0,0,0};
        int sl = oslot[t], gm = ogm[t];
        float s = 0.f;
        #pragma unroll
        for (int g = 0; g < 16; ++g) {
            float p = red[g][sl];
            s += (__popc(g & gm) & 1) ? -p : p;
        }
        out[row * NOBS + t] = s * scales[t] + biases[t];
    }
}

extern "C" void kernel_launch(void* const* d_in, const int* in_sizes, int n_in,
                              void* d_out, int out_size, void* d_ws, size_t ws_size,
                              hipStream_t stream) {
    const int Bn = in_sizes[0] / IND;   // 1024
    pqm_kernel<<<dim3(Bn), dim3(BLK), 0, stream>>>(
        (const float*)d_in[0], (const float*)d_in[1], (const float*)d_in[2],
        (const float*)d_in[3], (const float*)d_in[4], (const float*)d_in[5],
        (const float*)d_in[6], (const float*)d_in[7], (const float*)d_in[8],
        (const float*)d_in[9], (const float*)d_in[10], (const float*)d_in[11],
        (float*)d_out);
}

// Round 7
// 42.226 us; speedup vs baseline: 1.8117x; 1.0471x over previous
//
#include <hip/hip_runtime.h>
#include <math.h>

#define NQ   12
#define BLK  64
#define IND  768
#define HD   24
#define NOBS 28

typedef float  f32x2 __attribute__((ext_vector_type(2)));
typedef __fp16 f16x2 __attribute__((ext_vector_type(2)));

// ---- fp16 state pack/unpack (compute stays f32) ----
__device__ __forceinline__ unsigned pack2(f32x2 v) {
    f16x2 h = __builtin_amdgcn_cvt_pkrtz(v.x, v.y);
    unsigned u; __builtin_memcpy(&u, &h, 4); return u;
}
__device__ __forceinline__ f32x2 unpack2(unsigned u) {
    f16x2 h; __builtin_memcpy(&h, &u, 4);
    f32x2 v; v.x = (float)h.x; v.y = (float)h.y; return v;
}

// ---- packed complex arithmetic (VOP3P, 2 FMA per instruction) ----
__device__ __forceinline__ f32x2 pk_cmul(f32x2 m, f32x2 u) {
    f32x2 r;
    asm("v_pk_mul_f32 %0, %1, %2 op_sel:[0,0] op_sel_hi:[0,1]"
        : "=v"(r) : "v"(m), "v"(u));
    asm("v_pk_fma_f32 %0, %1, %2, %0 op_sel:[1,1,0] op_sel_hi:[1,0,1] neg_lo:[0,1,0]"
        : "+v"(r) : "v"(m), "v"(u));
    return r;
}
__device__ __forceinline__ void pk_cfma(f32x2& acc, f32x2 m, f32x2 u) {
    asm("v_pk_fma_f32 %0, %1, %2, %0 op_sel:[0,0,0] op_sel_hi:[0,1,1]"
        : "+v"(acc) : "v"(m), "v"(u));
    asm("v_pk_fma_f32 %0, %1, %2, %0 op_sel:[1,1,0] op_sel_hi:[1,0,1] neg_lo:[0,1,0]"
        : "+v"(acc) : "v"(m), "v"(u));
}
__device__ __forceinline__ void pk_fma_plain(f32x2& acc, f32x2 a, f32x2 b) {
    asm("v_pk_fma_f32 %0, %1, %2, %0" : "+v"(acc) : "v"(a), "v"(b));
}

// One 2x2 complex gate level on register bit M (compile-time), full 64-amp state.
template<int M>
__device__ __forceinline__ void glevel(f32x2* v, const float* Mp) {
    f32x2 M0 = *(const f32x2*)(Mp + 0);
    f32x2 M1 = *(const f32x2*)(Mp + 2);
    f32x2 M2 = *(const f32x2*)(Mp + 4);
    f32x2 M3 = *(const f32x2*)(Mp + 6);
    #pragma unroll
    for (int r = 0; r < 64; ++r)
        if (!(r & M)) {
            f32x2 u = v[r], w = v[r | M];
            f32x2 un = pk_cmul(M0, u); pk_cfma(un, M1, w);
            f32x2 wn = pk_cmul(M2, u); pk_cfma(wn, M3, w);
            v[r] = un; v[r | M] = wn;
        }
}

__global__ void __launch_bounds__(BLK) pqm_kernel(
    const float* __restrict__ x,   const float* __restrict__ W1,
    const float* __restrict__ b1,  const float* __restrict__ ln_g,
    const float* __restrict__ ln_b,const float* __restrict__ W2,
    const float* __restrict__ b2,  const float* __restrict__ qw0,
    const float* __restrict__ qw1, const float* __restrict__ qw2,
    const float* __restrict__ scales, const float* __restrict__ biases,
    float* __restrict__ out)
{
    __shared__ unsigned st[4096];     // fp16 state transpose buffer (16 KB)
    __shared__ float GMf[3][NQ][8];   // fused gate matrices
    __shared__ float hb[HD];
    __shared__ float ang[2 * NQ];
    __shared__ float obsl[NOBS];

    const int l   = threadIdx.x;      // lane 0..63 (single wave per block)
    const int row = blockIdx.x;

    // ---- Phase 1: stage x row into LDS (coalesced float4) ----
    float* xs = (float*)st;
    {
        const float4* xg = (const float4*)(x + row * IND);
        #pragma unroll
        for (int k = 0; k < 3; ++k)
            ((float4*)xs)[l + 64 * k] = xg[l + 64 * k];
    }
    __syncthreads();

    // ---- Phase 2: h = x@W1^T + b1 : 3 rounds of 8 outputs x 8 lanes ----
    {
        int l8 = l & 7;
        #pragma unroll
        for (int rd = 0; rd < 3; ++rd) {
            int g = rd * 8 + (l >> 3);
            const float* wp = W1 + g * IND + l8 * 96;
            const float* xp = xs + l8 * 96;
            float acc = 0.f;
            #pragma unroll
            for (int j = 0; j < 24; ++j) {
                float4 w4 = *(const float4*)(wp + 4 * j);
                float4 a4 = *(const float4*)(xp + 4 * j);
                acc += a4.x * w4.x + a4.y * w4.y + a4.z * w4.z + a4.w * w4.w;
            }
            acc += __shfl_down(acc, 4, 8);
            acc += __shfl_down(acc, 2, 8);
            acc += __shfl_down(acc, 1, 8);
            if (l8 == 0) hb[g] = acc + b1[g];
        }
    }
    __syncthreads();

    // ---- Phase 3: LN+ReLU+W2+tanh -> angles (lanes 0-11); Rot mats (12-47) ----
    if (l < NQ) {
        float mu = 0.f;
        #pragma unroll
        for (int j = 0; j < HD; ++j) mu += hb[j];
        mu *= (1.f / HD);
        float var = 0.f;
        #pragma unroll
        for (int j = 0; j < HD; ++j) { float d = hb[j] - mu; var += d * d; }
        var *= (1.f / HD);
        float rinv = 1.f / sqrtf(var + 1e-5f);
        float acc = b2[l];
        #pragma unroll
        for (int j = 0; j < HD; ++j) {
            float hn = (hb[j] - mu) * rinv * ln_g[j] + ln_b[j];
            acc += fmaxf(hn, 0.f) * W2[l * HD + j];
        }
        float a = tanhf(acc);
        ang[l]      = cosf(0.5f * a);
        ang[NQ + l] = sinf(0.5f * a);
    } else if (l < 48) {
        int li = (l - 12) / NQ, q = (l - 12) % NQ;
        const float* qw = (li == 0) ? qw0 : ((li == 1) ? qw1 : qw2);
        float phi = qw[q*3+0], th = qw[q*3+1], om = qw[q*3+2];
        float c = cosf(0.5f*th), s = sinf(0.5f*th);
        float sp, cp, sm, cm;
        sincosf(0.5f*(phi+om), &sp, &cp);
        sincosf(0.5f*(phi-om), &sm, &cm);
        float* R = GMf[li][q];
        R[0] =  cp*c;  R[1] = -sp*c;
        R[2] = -cm*s;  R[3] = -sm*s;
        R[4] =  cm*s;  R[5] = -sm*s;
        R[6] =  cp*c;  R[7] =  sp*c;
    }
    __syncthreads();
    // fuse M = Rot * RY in place
    if (l < 36) {
        int li = l / NQ, q = l % NQ;
        float* R = GMf[li][q];
        float r0=R[0],r1=R[1],r2=R[2],r3=R[3],r4=R[4],r5=R[5],r6=R[6],r7=R[7];
        float cr = ang[q], sr = ang[NQ + q];
        R[0] =  r0*cr + r2*sr;  R[1] =  r1*cr + r3*sr;
        R[2] = -r0*sr + r2*cr;  R[3] = -r1*sr + r3*cr;
        R[4] =  r4*cr + r6*sr;  R[5] =  r5*cr + r7*sr;
        R[6] = -r4*sr + r6*cr;  R[7] = -r5*sr + r7*cr;
    }
    __syncthreads();

    // ================= statevector in registers =================
    // Layout Q: lane bits = idx bits 0-5 (qubits 11..6), reg bits = idx 6-11 (qubits 5..0)
    // Layout P: lane bits = idx bits 6-11, reg bits = idx 0-5 (qubits 11..6)
    // LDS slot for idx: a(idx) = (lo6 << 6) | (hi6 ^ lo6)   (conflict-free all phases)
    f32x2 v[64];

    // ---- layer-0 gates via tensor-product init (layout Q) ----
    {
        f32x2 lf; lf.x = 1.f; lf.y = 0.f;
        #pragma unroll
        for (int lb = 0; lb < 6; ++lb) {           // lane bit lb -> qubit 11-lb
            const float* Fq = GMf[0][11 - lb];
            int bit = (l >> lb) & 1;
            f32x2 f; f.x = bit ? Fq[4] : Fq[0]; f.y = bit ? Fq[5] : Fq[1];
            lf = pk_cmul(f, lf);
        }
        {   // reg bit 0 -> qubit 5
            const float* Fq = GMf[0][5];
            f32x2 f0 = {Fq[0], Fq[1]}, f1 = {Fq[4], Fq[5]};
            v[0] = pk_cmul(f0, lf); v[1] = pk_cmul(f1, lf);
        }
        #define STAGE(B, Q) { \
            const float* Fq = GMf[0][Q]; \
            f32x2 f0 = {Fq[0], Fq[1]}, f1 = {Fq[4], Fq[5]}; \
            _Pragma("unroll") \
            for (int r = 0; r < (1 << B); ++r) { \
                v[r | (1 << B)] = pk_cmul(f1, v[r]); \
                v[r] = pk_cmul(f0, v[r]); } }
        STAGE(1, 4) STAGE(2, 3) STAGE(3, 2) STAGE(4, 1) STAGE(5, 0)
        #undef STAGE
    }

    const int lw  = l * 65;                        // Q-layout LDS dword base
    const int Bl  = l ^ (l >> 1);
    const int rb0 = ((l & 1) ? 0x820 : 0) ^ Bl;    // ring-read lane base

    // ringT: write layout Q, read layout P with CNOT-ring perm folded in
    #define RING_T() { \
        _Pragma("unroll") \
        for (int r = 0; r < 64; ++r) st[lw ^ r] = pack2(v[r]); \
        __syncthreads(); \
        _Pragma("unroll") \
        for (int r = 0; r < 64; ++r) { \
            const int sl0 = r ^ (r >> 1); \
            const int K = sl0 ^ (sl0 << 6) ^ ((r & 1) ? 0x30 : 0); \
            v[r] = unpack2(st[rb0 ^ K]); } }

    // midT: write layout P, read layout Q
    #define MID_T() { \
        _Pragma("unroll") \
        for (int r = 0; r < 64; ++r) st[(r * 65) ^ l] = pack2(v[r]); \
        __syncthreads(); \
        _Pragma("unroll") \
        for (int r = 0; r < 64; ++r) v[r] = unpack2(st[lw ^ r]); }

    RING_T();   // ring after layer 0 -> layout P

    for (int li = 1; li <= 2; ++li) {
        // P-phase gates: reg bit rb -> idx bit rb -> qubit 11-rb
        glevel< 1>(v, GMf[li][11]); glevel< 2>(v, GMf[li][10]);
        glevel< 4>(v, GMf[li][ 9]); glevel< 8>(v, GMf[li][ 8]);
        glevel<16>(v, GMf[li][ 7]); glevel<32>(v, GMf[li][ 6]);
        __syncthreads();
        MID_T();    // -> layout Q
        // Q-phase gates: reg bit rb -> idx bit 6+rb -> qubit 5-rb
        glevel< 1>(v, GMf[li][5]); glevel< 2>(v, GMf[li][4]);
        glevel< 4>(v, GMf[li][3]); glevel< 8>(v, GMf[li][2]);
        glevel<16>(v, GMf[li][1]); glevel<32>(v, GMf[li][0]);
        if (li == 1) { __syncthreads(); RING_T(); }   // ring -> layout P
    }
    // final ring (layer 2) folded into measurement masks; state in layout Q.

    // ================= measurement (layout Q) =================
    // eX q0..4: pre-ring masks 0xC00,0x600,0x300,0x180,0xC0 -> reg-pair masks
    float ex[5];
    #define EXACC(i, MM) { \
        f32x2 a0 = {0.f,0.f}, a1 = {0.f,0.f}, a2 = {0.f,0.f}, a3 = {0.f,0.f}; \
        _Pragma("unroll") \
        for (int r = 0; r < 64; r += 4) { \
            pk_fma_plain(a0, v[r],     v[(r)     ^ MM]); \
            pk_fma_plain(a1, v[r + 1], v[(r + 1) ^ MM]); \
            pk_fma_plain(a2, v[r + 2], v[(r + 2) ^ MM]); \
            pk_fma_plain(a3, v[r + 3], v[(r + 3) ^ MM]); } \
        ex[i] = a0.x + a0.y + a1.x + a1.y + a2.x + a2.y + a3.x + a3.y; }
    EXACC(0, 0x30) EXACC(1, 0x18) EXACC(2, 0x0C) EXACC(3, 6) EXACC(4, 3)
    #undef EXACC

    // probabilities into v[].x, then 64-pt WHT over reg bits
    #pragma unroll
    for (int r = 0; r < 64; ++r) v[r].x = v[r].x * v[r].x + v[r].y * v[r].y;
    #pragma unroll
    for (int lev = 0; lev < 6; ++lev) {
        const int m = 1 << lev;
        #pragma unroll
        for (int r = 0; r < 64; ++r)
            if (!(r & m)) {
                float A = v[r].x, B = v[r | m].x;
                v[r].x = A + B; v[r | m].x = A - B;
            }
    }

    auto laneWHT = [&](float s) {
        #pragma unroll
        for (int lev = 0; lev < 6; ++lev) {
            float o = __shfl_xor(s, 1 << lev, 64);
            s = (l & (1 << lev)) ? (o - s) : (s + o);
        }
        return s;
    };
    auto wsum = [&](float s) {
        #pragma unroll
        for (int d = 1; d < 64; d <<= 1) s += __shfl_xor(s, d, 64);
        return s;
    };

    // channels (pre-ring Z masks conjugated through final ring):
    float chA = laneWHT(v[0x3F].x);   // Mr=0x3F: eZ q5..q11 on lanes 0,32,48,56,60,62,63
    float chB = laneWHT(v[0x00].x);   // Mr=0:    eZZ q5..q10 on lanes 32,16,8,4,2,1
    float p30 = wsum(v[0x30].x);      // eZ q1
    float p38 = wsum(v[0x38].x);      // eZ q2
    float p3C = wsum(v[0x3C].x);      // eZ q3
    float p3E = wsum(v[0x3E].x);      // eZ q4
    float p8  = wsum(v[8].x);         // eZZ q1
    float p4  = wsum(v[4].x);         // eZZ q2
    float p2  = wsum(v[2].x);         // eZZ q3
    float p1  = wsum(v[1].x);         // eZZ q4
    float sgn = (__popc(l) & 1) ? -1.f : 1.f;
    float sZ0  = wsum(sgn * v[0x1F].x);   // eZ q0  (Mr=0x1F, Ml=0x3F)
    float sZZ0 = wsum(sgn * v[0x2F].x);   // eZZ q0 (Mr=0x2F, Ml=0x3F)
    float ex0 = wsum(ex[0]), ex1 = wsum(ex[1]), ex2 = wsum(ex[2]);
    float ex3 = wsum(ex[3]), ex4 = wsum(ex[4]);

    // stage observables
    if (l == 0) {
        obsl[0] = sZ0;  obsl[12] = sZZ0;
        obsl[1] = p30;  obsl[2] = p38;  obsl[3] = p3C;  obsl[4] = p3E;
        obsl[13] = p8;  obsl[14] = p4;  obsl[15] = p2;  obsl[16] = p1;
        obsl[23] = ex0; obsl[24] = ex1; obsl[25] = ex2;
        obsl[26] = ex3; obsl[27] = ex4;
        obsl[5] = chA;
    }
    if (l == 32) { obsl[6]  = chA; obsl[17] = chB; }
    if (l == 48) obsl[7]  = chA;
    if (l == 56) obsl[8]  = chA;
    if (l == 60) obsl[9]  = chA;
    if (l == 62) obsl[10] = chA;
    if (l == 63) obsl[11] = chA;
    if (l == 16) obsl[18] = chB;
    if (l == 8)  obsl[19] = chB;
    if (l == 4)  obsl[20] = chB;
    if (l == 2)  obsl[21] = chB;
    if (l == 1)  obsl[22] = chB;
    __syncthreads();

    if (l < NOBS)
        out[row * NOBS + l] = obsl[l] * scales[l] + biases[l];
}

extern "C" void kernel_launch(void* const* d_in, const int* in_sizes, int n_in,
                              void* d_out, int out_size, void* d_ws, size_t ws_size,
                              hipStream_t stream) {
    const int Bn = in_sizes[0] / IND;   // 1024
    pqm_kernel<<<dim3(Bn), dim3(BLK), 0, stream>>>(
        (const float*)d_in[0], (const float*)d_in[1], (const float*)d_in[2],
        (const float*)d_in[3], (const float*)d_in[4], (const float*)d_in[5],
        (const float*)d_in[6], (const float*)d_in[7], (const float*)d_in[8],
        (const float*)d_in[9], (const float*)d_in[10], (const float*)d_in[11],
        (float*)d_out);
}